// Round 1
// 54.719 us; speedup vs baseline: 1.0065x; 1.0065x over previous
//
#include <hip/hip_runtime.h>

// QuantumLLPModel: probs[b, j<10] of a 14-qubit product state.
// Only qubits 10..13 matter: the common factor prod_{i<10} p0[b,i]
// cancels under normalization. One v_cos per qubit (revolution form).
//
// Factorization: j = 4*hi + lo, hi=j>>2 in {0,1,2} (qubits 10,11),
// lo=j&3 (qubits 12,13). q[j] = A[hi]*B[lo].
// Denominator telescopes: sum_{j<10} = p0_10 + p1_10*p0_11*p0_12
// (since sum_{j>=10} = p1_10*(1 - p0_11*p0_12), and total sum = 1).

#define NQ 14
#define NOUT 10
#define INV2PI 0.15915494309189535f

__global__ __launch_bounds__(256) void quantum_llp_kernel(
    const float* __restrict__ x,       // [B, 14]
    const float* __restrict__ params,  // [14]
    float* __restrict__ out,           // [B, 10]
    int B)
{
    int b = blockIdx.x * blockDim.x + threadIdx.x;
    if (b >= B) return;

    // x[b,10..13]: byte offset 56b+40 is 8B-aligned -> two dwordx2 loads.
    const float2* xr = reinterpret_cast<const float2*>(x + b * NQ + (NQ - 4));
    float2 x01 = xr[0];
    float2 x23 = xr[1];
    float xv[4] = {x01.x, x01.y, x23.x, x23.y};

    // cos(pi*x + p) = cos(2*pi*(0.5*x + p/(2*pi))); v_cos takes revolutions.
    float p0v[4], p1v[4];
#pragma unroll
    for (int k = 0; k < 4; ++k) {
        float prev = params[NQ - 4 + k] * INV2PI;  // uniform -> scalar-cached
        float r = fmaf(0.5f, xv[k], prev);
        r = r - floorf(r);                          // reduce to [0,1)
        float c = __builtin_amdgcn_cosf(r);
        p0v[k] = 0.5f * (1.0f + c);
        p1v[k] = 0.5f * (1.0f - c);
    }

    // hi bits (b3,b2) -> qubits 10,11 ; lo bits (b1,b0) -> qubits 12,13
    float Ah[3] = { p0v[0] * p0v[1],    // hi=0
                    p0v[0] * p1v[1],    // hi=1
                    p1v[0] * p0v[1] };  // hi=2
    float Bl[4] = { p0v[2] * p0v[3],
                    p0v[2] * p1v[3],
                    p1v[2] * p0v[3],
                    p1v[2] * p1v[3] };

    // Telescoped denominator; s in (0,1], v_rcp (1 ulp) is fine vs 2^-9 tol.
    float s = fmaf(p1v[0] * p0v[1], p0v[2], p0v[0]);
    float inv = __builtin_amdgcn_rcpf(s);
    Ah[0] *= inv; Ah[1] *= inv; Ah[2] *= inv;

    float q[NOUT];
#pragma unroll
    for (int j = 0; j < NOUT; ++j) q[j] = Ah[j >> 2] * Bl[j & 3];

    // out row: byte offset 40b is 8B-aligned -> five dwordx2 stores.
    float2* o = reinterpret_cast<float2*>(out + b * NOUT);
#pragma unroll
    for (int k = 0; k < 5; ++k) o[k] = make_float2(q[2 * k], q[2 * k + 1]);
}

extern "C" void kernel_launch(void* const* d_in, const int* in_sizes, int n_in,
                              void* d_out, int out_size, void* d_ws, size_t ws_size,
                              hipStream_t stream) {
    const float* x      = (const float*)d_in[0];  // [B,14] f32
    const float* params = (const float*)d_in[1];  // [14]   f32
    float* out          = (float*)d_out;          // [B,10] f32

    int B = in_sizes[0] / NQ;  // 8192
    int block = 256;
    int grid = (B + block - 1) / block;
    quantum_llp_kernel<<<grid, block, 0, stream>>>(x, params, out, B);
}